// Round 10
// baseline (21.711 us; speedup 1.0000x reference)
//
#include <hip/hip_runtime.h>
#include <math.h>

constexpr int kB = 2, kP = 300, kF = 512, kH = 128, kW = 128, kTH = 512, kTW = 512;
constexpr float kDelta = 7000.0f;
constexpr float kCut = 0.0363f;    // skip p < ~1e-4 contributions (improb err <= ~1e-3)
constexpr float kThr2 = 0.012928f; // (kCut + 0.0774 pixel-center tile radius)^2
constexpr float kLogInside = -15.9423847f; // log1p(-(1-1e-7f)) = ln(2^-23)

// One fused kernel. Grid: 256 blocks = 2 batches x 128 tile-PAIRS; each block
// renders two horizontally adjacent 8x8 tiles (tx = txp*2 + it).
// Block: 512 threads = 8 waves. Compacted front-face k DEALT to slot
// (k&7)*64 + (k>>3): wave wv owns slots [wv*64,wv*64+64) = faces k===wv (mod 8).
// L_i(p) = A_i px + B_i py + C_i = signed distance to edge-line i (unit normal).
__global__ __launch_bounds__(512, 6) void render_all(const float* __restrict__ pts,
                                                     const int* __restrict__ faces,
                                                     const float* __restrict__ uvs,
                                                     const float* __restrict__ tex,
                                                     float* __restrict__ out) {
    __shared__ float4 sA[kF], sB[kF], sC[kF];   // 24 KB hot records
    __shared__ float2 s_vtx[kF * 3];            // 12 KB verts (xy)
    __shared__ ushort4 s_j3[kF];                // 4 KB vertex indices
    __shared__ float s_uv[kP * 2];              // 2.4 KB staged uvs (batch b)
    __shared__ float s_bz[512];                 // loop-result arrays
    __shared__ int s_bi[512];
    __shared__ float s_lm[512];
    __shared__ float4 s_pxW[64];                // per-pixel bilinear weights * mk
    __shared__ int4 s_pxO[64];                  // per-pixel texel offsets
    __shared__ int s_wsum[8];

    int blk = (int)blockIdx.x;
    int b = blk >> 7;          // batch
    int rem = blk & 127;       // tile pair
    int ty = rem >> 3;
    int txp = rem & 7;
    int tid = (int)threadIdx.x;
    int lane = tid & 63;
    int wv = tid >> 6;

    // ---------- setup (once per block): thread tid processes face tid ----------
    {
        int f = tid;
        int i0 = faces[f * 3 + 0], i1 = faces[f * 3 + 1], i2 = faces[f * 3 + 2];
        const float* pb = pts + b * kP * 3;
        float x0 = pb[i0 * 3], y0 = pb[i0 * 3 + 1], z0 = pb[i0 * 3 + 2];
        float x1 = pb[i1 * 3], y1 = pb[i1 * 3 + 1], z1 = pb[i1 * 3 + 2];
        float x2 = pb[i2 * 3], y2 = pb[i2 * 3 + 1], z2 = pb[i2 * 3 + 2];
        float area = (x1 - x0) * (y2 - y0) - (y1 - y0) * (x2 - x0);
        bool front = area > 1e-8f;

        const float* gu = uvs + b * (kP * 2);
        for (int i = tid; i < kP * 2; i += 512) s_uv[i] = gu[i];
        // prefill: empty slots never inside / never admitted, NaN-free
        sA[f] = make_float4(0.0f, 0.0f, -1e30f, 0.0f);
        sB[f] = make_float4(0.0f, -1e30f, 0.0f, 0.0f);
        sC[f] = make_float4(-1e30f, 0.0f, 0.0f, 0.0f);
        s_vtx[f * 3 + 0] = make_float2(1e15f, 1e15f);
        s_vtx[f * 3 + 1] = make_float2(1e15f, 1e15f);
        s_vtx[f * 3 + 2] = make_float2(1e15f, 1e15f);
        unsigned long long bal = __ballot(front);
        if (lane == 0) s_wsum[wv] = __popcll(bal);
        __syncthreads();  // wsum + prefill visible

        int base = 0;
#pragma unroll
        for (int w = 0; w < 8; ++w) base += (w < wv) ? s_wsum[w] : 0;
        int k = base + __popcll(bal & ((1ull << lane) - 1ull));  // compacted idx

        if (front) {
            int slot = ((k & 7) << 6) | (k >> 3);  // deal across waves
            float inv_a = 1.0f / area;
            float e0x = x2 - x1, e0y = y2 - y1;
            float e1x = x0 - x2, e1y = y0 - y2;
            float e2x = x1 - x0, e2y = y1 - y0;
            float l0 = fmaf(e0x, e0x, e0y * e0y);
            float l1 = fmaf(e1x, e1x, e1y * e1y);
            float l2 = fmaf(e2x, e2x, e2y * e2y);
            float s0 = rsqrtf(l0 + 1e-12f);
            float s1 = rsqrtf(l1 + 1e-12f);
            float s2 = rsqrtf(l2 + 1e-12f);
            float A0 = -e0y * s0, B0 = e0x * s0, C0 = (e0y * x1 - e0x * y1) * s0;
            float A1 = -e1y * s1, B1 = e1x * s1, C1 = (e1y * x2 - e1x * y2) * s1;
            float A2 = -e2y * s2, B2 = e2x * s2, C2 = (e2y * x0 - e2x * y0) * s2;
            float a0 = -e0y * inv_a, b0 = e0x * inv_a, c0 = (e0y * x1 - e0x * y1) * inv_a;
            float a1 = -e1y * inv_a, b1 = e1x * inv_a, c1 = (e1y * x2 - e1x * y2) * inv_a;
            float a2 = -e2y * inv_a, b2 = e2x * inv_a, c2 = (e2y * x0 - e2x * y0) * inv_a;
            sA[slot] = make_float4(A0, B0, C0, A1);
            sB[slot] = make_float4(B1, C1, A2, B2);
            sC[slot] = make_float4(C2,
                                   a0 * z0 + a1 * z1 + a2 * z2,
                                   b0 * z0 + b1 * z1 + b2 * z2,
                                   c0 * z0 + c1 * z1 + c2 * z2);
            s_vtx[slot * 3 + 0] = make_float2(x0, y0);
            s_vtx[slot * 3 + 1] = make_float2(x1, y1);
            s_vtx[slot * 3 + 2] = make_float2(x2, y2);
            s_j3[slot] = make_ushort4((unsigned short)i0, (unsigned short)i1,
                                      (unsigned short)i2, 0);
        }
    }
    __syncthreads();

    // ---------- per-tile render: it = 0,1 ----------
    for (int it = 0; it < 2; ++it) {
        int tx = txp * 2 + it;
        int pyi = ty * 8 + (lane >> 3);
        int pxi = tx * 8 + (lane & 7);
        float px = ((float)pxi + 0.5f) * (2.0f / 128.0f) - 1.0f;
        float py = 1.0f - ((float)pyi + 0.5f) * (2.0f / 128.0f);

        // cull: lane l tests slot wv*64+l, exact dist-to-triangle at tile center
        float cx = (float)(tx * 8 + 4) * (2.0f / 128.0f) - 1.0f;
        float cy = 1.0f - (float)(ty * 8 + 4) * (2.0f / 128.0f);
        unsigned long long m;
        {
            int slt = (wv << 6) + lane;
            float4 a4 = sA[slt];
            float4 b4 = sB[slt];
            float4 c4 = sC[slt];
            float L0 = fmaf(a4.x, cx, fmaf(a4.y, cy, a4.z));
            float L1 = fmaf(a4.w, cx, fmaf(b4.x, cy, b4.y));
            float L2 = fmaf(b4.z, cx, fmaf(b4.w, cy, c4.x));
            float minc = fminf(fminf(L0, L1), L2);
            float2 v0 = s_vtx[slt * 3 + 0];
            float2 v1 = s_vtx[slt * 3 + 1];
            float2 v2 = s_vtx[slt * 3 + 2];
            float e0x = v2.x - v1.x, e0y = v2.y - v1.y;
            float e1x = v0.x - v2.x, e1y = v0.y - v2.y;
            float e2x = v1.x - v0.x, e2y = v1.y - v0.y;
            float p0x = cx - v0.x, p0y = cy - v0.y;
            float p1x = cx - v1.x, p1y = cy - v1.y;
            float p2x = cx - v2.x, p2y = cy - v2.y;
            float dot0 = fmaf(p1x, e0x, p1y * e0y), len0 = fmaf(e0x, e0x, e0y * e0y);
            float dot1 = fmaf(p2x, e1x, p2y * e1y), len1 = fmaf(e1x, e1x, e1y * e1y);
            float dot2 = fmaf(p0x, e2x, p0y * e2y), len2 = fmaf(e2x, e2x, e2y * e2y);
            float c0 = (dot0 >= 0.0f && dot0 <= len0) ? L0 * L0 : 1e30f;
            float c1 = (dot1 >= 0.0f && dot1 <= len1) ? L1 * L1 : 1e30f;
            float c2 = (dot2 >= 0.0f && dot2 <= len2) ? L2 * L2 : 1e30f;
            float dv0 = fmaf(p0x, p0x, p0y * p0y);
            float dv1 = fmaf(p1x, p1x, p1y * p1y);
            float dv2 = fmaf(p2x, p2x, p2y * p2y);
            float d2c = fminf(fminf(fminf(c0, c1), fminf(c2, dv0)), fminf(dv1, dv2));
            bool admit = (minc >= 0.0f) | (d2c <= kThr2);
            m = __ballot(admit);
        }

        float bestz = -1e9f;
        int besti = -1, icnt = 0;  // besti = compacted index k (global face order)
        float lm = 0.0f;

        while (m) {
            int l = (int)__builtin_ctzll(m);
            m &= (m - 1);
            int fs = (wv << 6) + l;  // LDS slot (wave-uniform)
            int k = (l << 3) | wv;   // compacted face index, ascending in l
            float4 h0 = sA[fs];
            float4 h1 = sB[fs];
            float4 h2 = sC[fs];
            float L0 = fmaf(h0.x, px, fmaf(h0.y, py, h0.z));
            float L1 = fmaf(h0.w, px, fmaf(h1.x, py, h1.y));
            float L2 = fmaf(h1.z, px, fmaf(h1.w, py, h2.x));
            float minL = fminf(fminf(L0, L1), L2);
            bool inside = minL >= 0.0f;
            float z = fmaf(h2.y, px, fmaf(h2.z, py, h2.w));
            if (inside && z > bestz) { bestz = z; besti = k; }
            icnt += inside ? 1 : 0;
            float db = fminf(fminf(fabsf(L0), fabsf(L1)), fabsf(L2));
            bool need = (!inside) & (db < kCut);
            if (__any(need)) {
                float2 v0 = s_vtx[fs * 3 + 0];
                float2 v1 = s_vtx[fs * 3 + 1];
                float2 v2 = s_vtx[fs * 3 + 2];
                float e0x = v2.x - v1.x, e0y = v2.y - v1.y;
                float e1x = v0.x - v2.x, e1y = v0.y - v2.y;
                float e2x = v1.x - v0.x, e2y = v1.y - v0.y;
                float p0x = px - v0.x, p0y = py - v0.y;
                float p1x = px - v1.x, p1y = py - v1.y;
                float p2x = px - v2.x, p2y = py - v2.y;
                float dot0 = fmaf(p1x, e0x, p1y * e0y), len0 = fmaf(e0x, e0x, e0y * e0y);
                float dot1 = fmaf(p2x, e1x, p2y * e1y), len1 = fmaf(e1x, e1x, e1y * e1y);
                float dot2 = fmaf(p0x, e2x, p0y * e2y), len2 = fmaf(e2x, e2x, e2y * e2y);
                float c0 = (dot0 >= 0.0f && dot0 <= len0) ? L0 * L0 : 1e30f;
                float c1 = (dot1 >= 0.0f && dot1 <= len1) ? L1 * L1 : 1e30f;
                float c2 = (dot2 >= 0.0f && dot2 <= len2) ? L2 * L2 : 1e30f;
                float dv0 = fmaf(p0x, p0x, p0y * p0y);
                float dv1 = fmaf(p1x, p1x, p1y * p1y);
                float dv2 = fmaf(p2x, p2x, p2y * p2y);
                float d2 = fminf(fminf(fminf(c0, c1), fminf(c2, dv0)), fminf(dv1, dv2));
                float p = __expf(-kDelta * d2);
                p = fminf(p, 1.0f - 1e-7f);
                float lp = __logf(1.0f - p);  // == log1p(-p) over admitted range
                lm += need ? lp : 0.0f;
            }
        }
        lm = fmaf((float)icnt, kLogInside, lm);

        s_bz[tid] = bestz;
        s_bi[tid] = besti;
        s_lm[tid] = lm;
        __syncthreads();

        // reduce + fragment prep (wave 0)
        if (tid < 64) {
            float bz = s_bz[tid];
            int bi = s_bi[tid];
            float L = s_lm[tid];
#pragma unroll
            for (int w = 1; w < 8; ++w) {
                float z2 = s_bz[w * 64 + tid];
                int ii = s_bi[w * 64 + tid];
                L += s_lm[w * 64 + tid];
                // first-max: lowest compacted index (earliest original face) wins
                if (z2 > bz || (z2 == bz && ii >= 0 && (unsigned)ii < (unsigned)bi)) {
                    bz = z2; bi = ii;
                }
            }
            float improb = 1.0f - expf(L);
            float u = 0.0f, v = 0.0f, mk = 0.0f;
            if (bi >= 0) {
                int slot = ((bi & 7) << 6) | (bi >> 3);
                float2 v0 = s_vtx[slot * 3 + 0];
                float2 v1 = s_vtx[slot * 3 + 1];
                float2 v2 = s_vtx[slot * 3 + 2];
                float area = (v1.x - v0.x) * (v2.y - v0.y) - (v1.y - v0.y) * (v2.x - v0.x);
                float inv_a = 1.0f / area;
                // exact reference formulation
                float w0 = ((v2.x - v1.x) * (py - v1.y) - (v2.y - v1.y) * (px - v1.x)) * inv_a;
                float w1 = ((v0.x - v2.x) * (py - v2.y) - (v0.y - v2.y) * (px - v2.x)) * inv_a;
                float w2 = ((v1.x - v0.x) * (py - v0.y) - (v1.y - v0.y) * (px - v0.x)) * inv_a;
                ushort4 j = s_j3[slot];
                u = w0 * s_uv[j.x * 2] + w1 * s_uv[j.y * 2] + w2 * s_uv[j.z * 2];
                v = w0 * s_uv[j.x * 2 + 1] + w1 * s_uv[j.y * 2 + 1] + w2 * s_uv[j.z * 2 + 1];
                mk = w0 + w1 + w2;
            }
            float uc = fminf(fmaxf(u, 0.0f), 1.0f);
            float vc = fminf(fmaxf(v, 0.0f), 1.0f);
            float fx = uc * (float)(kTW - 1);
            float fy = (1.0f - vc) * (float)(kTH - 1);
            int xi0 = (int)floorf(fx), yi0 = (int)floorf(fy);
            int xi1 = min(xi0 + 1, kTW - 1), yi1 = min(yi0 + 1, kTH - 1);
            float wx = fx - (float)xi0, wy = fy - (float)yi0;
            float w00 = (1.0f - wx) * (1.0f - wy) * mk;
            float w01 = wx * (1.0f - wy) * mk;
            float w10 = (1.0f - wx) * wy * mk;
            float w11 = wx * wy * mk;
            s_pxW[tid] = make_float4(w00, w01, w10, w11);
            s_pxO[tid] = make_int4(yi0 * kTW + xi0, yi0 * kTW + xi1,
                                   yi1 * kTW + xi0, yi1 * kTW + xi1);
            out[kB * kH * kW * 3 + (b * kH + pyi) * kW + pxi] = improb;
        }
        __syncthreads();

        // fragment shader: 192 threads = 64 px x 3 channels; threads >= 192
        // fall through to the next tile's cull/loop immediately (no barrier
        // needed: next writes to s_bz/... are ordered by the barrier above
        // on the next iteration, and s_pxW/s_pxO are rewritten only by
        // wave 0 after that barrier).
        if (tid < 192) {
            int pix = tid & 63;
            int c = tid >> 6;
            float4 w = s_pxW[pix];
            int4 o = s_pxO[pix];
            const float* tc = tex + ((size_t)b * 3 + c) * kTH * kTW;
            float col = tc[o.x] * w.x + tc[o.y] * w.y + tc[o.z] * w.z + tc[o.w] * w.w;
            int qy = ty * 8 + (pix >> 3);
            int qx = tx * 8 + (pix & 7);
            out[((b * kH + qy) * kW + qx) * 3 + c] = col;
        }
    }
}

extern "C" void kernel_launch(void* const* d_in, const int* in_sizes, int n_in,
                              void* d_out, int out_size, void* d_ws, size_t ws_size,
                              hipStream_t stream) {
    const float* pts = (const float*)d_in[0];
    const int* faces = (const int*)d_in[1];
    const float* uvs = (const float*)d_in[2];
    const float* tex = (const float*)d_in[3];
    float* out = (float*)d_out;
    render_all<<<kB * 128, 512, 0, stream>>>(pts, faces, uvs, tex, out);
}

// Round 11
// 18.353 us; speedup vs baseline: 1.1830x; 1.1830x over previous
//
#include <hip/hip_runtime.h>
#include <math.h>

constexpr int kB = 2, kP = 300, kF = 512, kH = 128, kW = 128, kTH = 512, kTW = 512;
constexpr float kDelta = 7000.0f;
constexpr float kCut = 0.0363f;    // skip p < ~1e-4 contributions (improb err <= ~1e-3)
constexpr float kThr2 = 0.012928f; // (kCut + 0.0774 pixel-center tile radius)^2
constexpr float kLogInside = -15.9423847f; // log1p(-(1-1e-7f)) = ln(2^-23)

__device__ __forceinline__ unsigned zmap(float f) {
    unsigned b = __float_as_uint(f);
    return (b & 0x80000000u) ? ~b : (b | 0x80000000u);  // order-preserving float->uint
}

// One fused kernel. Grid: 512 blocks = 2 batches x 256 tiles (8x8 px).
// Block: 512 threads = 8 waves; LDS <= 40KB -> 4 blocks/CU = 8 waves/SIMD.
// Compacted front-face k DEALT to slot (k&7)*64+(k>>3); wave wv owns slots
// [wv*64,wv*64+64) = faces k===wv (mod 8). L_i(p) = signed distance to edge
// line i (unit normal). v2 is derived as intersection of lines 0 and 1.
__global__ __launch_bounds__(512, 8) void render_all(const float* __restrict__ pts,
                                                     const int* __restrict__ faces,
                                                     const float* __restrict__ uvs,
                                                     const float* __restrict__ tex,
                                                     float* __restrict__ out) {
    __shared__ float4 sA[kF], sB[kF], sC[kF];      // 24 KB hot records
    __shared__ float4 sV[kF];                      // 8 KB: (x0,y0,x1,y1)
    __shared__ ushort4 s_j3[kF];                   // 4 KB vertex indices
    __shared__ float s_uv[kP * 2];                 // 2.4 KB staged uvs
    __shared__ unsigned long long s_best[64];      // 512 B packed (z | 511-k)
    __shared__ float s_lm[64];                     // 256 B log-miss accum
    __shared__ int s_wsum[8];                      // 32 B
    float4* s_pxW = sA;                            // aliases (sA dead post-loop)
    int4* s_pxO = (int4*)(sA + 64);

    int tile = (int)blockIdx.x;
    int b = tile >> 8;
    int rem = tile & 255;
    int ty = rem >> 4, tx = rem & 15;
    int tid = (int)threadIdx.x;
    int lane = tid & 63;
    int wv = tid >> 6;

    // ---------- setup: thread tid processes face tid for batch b ----------
    {
        int f = tid;
        int i0 = faces[f * 3 + 0], i1 = faces[f * 3 + 1], i2 = faces[f * 3 + 2];
        const float* pb = pts + b * kP * 3;
        float x0 = pb[i0 * 3], y0 = pb[i0 * 3 + 1], z0 = pb[i0 * 3 + 2];
        float x1 = pb[i1 * 3], y1 = pb[i1 * 3 + 1], z1 = pb[i1 * 3 + 2];
        float x2 = pb[i2 * 3], y2 = pb[i2 * 3 + 1], z2 = pb[i2 * 3 + 2];
        float area = (x1 - x0) * (y2 - y0) - (y1 - y0) * (x2 - x0);
        bool front = area > 1e-8f;

        const float* gu = uvs + b * (kP * 2);
        for (int i = tid; i < kP * 2; i += 512) s_uv[i] = gu[i];
        if (tid < 64) { s_best[tid] = 0ull; s_lm[tid] = 0.0f; }
        // prefill: empty slots never inside / never admitted, NaN-free
        sA[f] = make_float4(0.0f, 0.0f, -1e30f, 0.0f);
        sB[f] = make_float4(0.0f, -1e30f, 0.0f, 0.0f);
        sC[f] = make_float4(-1e30f, 0.0f, 0.0f, 0.0f);
        sV[f] = make_float4(1e15f, 1e15f, 1e15f, 1e15f);
        unsigned long long bal = __ballot(front);
        if (lane == 0) s_wsum[wv] = __popcll(bal);
        __syncthreads();  // wsum + prefill + inits visible

        int base = 0;
#pragma unroll
        for (int w = 0; w < 8; ++w) base += (w < wv) ? s_wsum[w] : 0;
        int k = base + __popcll(bal & ((1ull << lane) - 1ull));  // compacted idx

        if (front) {
            int slot = ((k & 7) << 6) | (k >> 3);  // deal across waves
            float inv_a = 1.0f / area;
            float e0x = x2 - x1, e0y = y2 - y1;
            float e1x = x0 - x2, e1y = y0 - y2;
            float e2x = x1 - x0, e2y = y1 - y0;
            float l0 = fmaf(e0x, e0x, e0y * e0y);
            float l1 = fmaf(e1x, e1x, e1y * e1y);
            float l2 = fmaf(e2x, e2x, e2y * e2y);
            float s0 = rsqrtf(l0 + 1e-12f);
            float s1 = rsqrtf(l1 + 1e-12f);
            float s2 = rsqrtf(l2 + 1e-12f);
            float A0 = -e0y * s0, B0 = e0x * s0, C0 = (e0y * x1 - e0x * y1) * s0;
            float A1 = -e1y * s1, B1 = e1x * s1, C1 = (e1y * x2 - e1x * y2) * s1;
            float A2 = -e2y * s2, B2 = e2x * s2, C2 = (e2y * x0 - e2x * y0) * s2;
            float a0 = -e0y * inv_a, b0 = e0x * inv_a, c0 = (e0y * x1 - e0x * y1) * inv_a;
            float a1 = -e1y * inv_a, b1 = e1x * inv_a, c1 = (e1y * x2 - e1x * y2) * inv_a;
            float a2 = -e2y * inv_a, b2 = e2x * inv_a, c2 = (e2y * x0 - e2x * y0) * inv_a;
            sA[slot] = make_float4(A0, B0, C0, A1);
            sB[slot] = make_float4(B1, C1, A2, B2);
            sC[slot] = make_float4(C2,
                                   a0 * z0 + a1 * z1 + a2 * z2,
                                   b0 * z0 + b1 * z1 + b2 * z2,
                                   c0 * z0 + c1 * z1 + c2 * z2);
            sV[slot] = make_float4(x0, y0, x1, y1);
            s_j3[slot] = make_ushort4((unsigned short)i0, (unsigned short)i1,
                                      (unsigned short)i2, 0);
        }
    }
    __syncthreads();

    // ---------- render ----------
    int pyi = ty * 8 + (lane >> 3);
    int pxi = tx * 8 + (lane & 7);
    float px = ((float)pxi + 0.5f) * (2.0f / 128.0f) - 1.0f;
    float py = 1.0f - ((float)pyi + 0.5f) * (2.0f / 128.0f);

    // cull: lane l tests slot wv*64+l, exact dist-to-triangle at tile center
    float cx = (float)(tx * 8 + 4) * (2.0f / 128.0f) - 1.0f;
    float cy = 1.0f - (float)(ty * 8 + 4) * (2.0f / 128.0f);
    unsigned long long m;
    {
        int slt = (wv << 6) + lane;
        float4 a4 = sA[slt];
        float4 b4 = sB[slt];
        float4 c4 = sC[slt];
        float4 vv = sV[slt];
        float L0 = fmaf(a4.x, cx, fmaf(a4.y, cy, a4.z));
        float L1 = fmaf(a4.w, cx, fmaf(b4.x, cy, b4.y));
        float L2 = fmaf(b4.z, cx, fmaf(b4.w, cy, c4.x));
        float minc = fminf(fminf(L0, L1), L2);
        // v2 = intersection of lines 0 and 1 (unit normals -> |D| = sin(angle))
        float D = fmaf(a4.x, b4.x, -a4.w * a4.y);        // A0*B1 - A1*B0
        float rD = __builtin_amdgcn_rcpf(D);
        float v2x = (a4.y * b4.y - b4.x * a4.z) * rD;    // (B0*C1 - B1*C0)/D
        float v2y = (a4.w * a4.z - a4.x * b4.y) * rD;    // (A1*C0 - A0*C1)/D
        float e0x = v2x - vv.z, e0y = v2y - vv.w;
        float e1x = vv.x - v2x, e1y = vv.y - v2y;
        float e2x = vv.z - vv.x, e2y = vv.w - vv.y;
        float p0x = cx - vv.x, p0y = cy - vv.y;
        float p1x = cx - vv.z, p1y = cy - vv.w;
        float p2x = cx - v2x, p2y = cy - v2y;
        float dot0 = fmaf(p1x, e0x, p1y * e0y), len0 = fmaf(e0x, e0x, e0y * e0y);
        float dot1 = fmaf(p2x, e1x, p2y * e1y), len1 = fmaf(e1x, e1x, e1y * e1y);
        float dot2 = fmaf(p0x, e2x, p0y * e2y), len2 = fmaf(e2x, e2x, e2y * e2y);
        float c0 = (dot0 >= 0.0f && dot0 <= len0) ? L0 * L0 : 1e30f;
        float c1 = (dot1 >= 0.0f && dot1 <= len1) ? L1 * L1 : 1e30f;
        float c2 = (dot2 >= 0.0f && dot2 <= len2) ? L2 * L2 : 1e30f;
        float dv0 = fmaf(p0x, p0x, p0y * p0y);
        float dv1 = fmaf(p1x, p1x, p1y * p1y);
        float dv2 = fmaf(p2x, p2x, p2y * p2y);
        float d2c = fminf(fminf(fminf(c0, c1), fminf(c2, dv0)), fminf(dv1, dv2));
        bool admit = (minc >= 0.0f) | (d2c <= kThr2);
        m = __ballot(admit);
    }

    float bestz = -1e9f;
    int besti = -1, icnt = 0;  // besti = compacted index k (global face order)
    float lm = 0.0f;

    while (m) {
        int l = (int)__builtin_ctzll(m);
        m &= (m - 1);
        int fs = (wv << 6) + l;  // LDS slot (wave-uniform)
        int k = (l << 3) | wv;   // compacted face index, ascending in l
        float4 h0 = sA[fs];
        float4 h1 = sB[fs];
        float4 h2 = sC[fs];
        float L0 = fmaf(h0.x, px, fmaf(h0.y, py, h0.z));
        float L1 = fmaf(h0.w, px, fmaf(h1.x, py, h1.y));
        float L2 = fmaf(h1.z, px, fmaf(h1.w, py, h2.x));
        float minL = fminf(fminf(L0, L1), L2);
        bool inside = minL >= 0.0f;
        float z = fmaf(h2.y, px, fmaf(h2.z, py, h2.w));
        if (inside && z > bestz) { bestz = z; besti = k; }
        icnt += inside ? 1 : 0;
        float db = fminf(fminf(fabsf(L0), fabsf(L1)), fabsf(L2));
        bool need = (!inside) & (db < kCut);
        if (__any(need)) {
            float4 vv = sV[fs];
            float D = fmaf(h0.x, h1.x, -h0.w * h0.y);
            float rD = __builtin_amdgcn_rcpf(D);
            float v2x = (h0.y * h1.y - h1.x * h0.z) * rD;
            float v2y = (h0.w * h0.z - h0.x * h1.y) * rD;
            float e0x = v2x - vv.z, e0y = v2y - vv.w;
            float e1x = vv.x - v2x, e1y = vv.y - v2y;
            float e2x = vv.z - vv.x, e2y = vv.w - vv.y;
            float p0x = px - vv.x, p0y = py - vv.y;
            float p1x = px - vv.z, p1y = py - vv.w;
            float p2x = px - v2x, p2y = py - v2y;
            float dot0 = fmaf(p1x, e0x, p1y * e0y), len0 = fmaf(e0x, e0x, e0y * e0y);
            float dot1 = fmaf(p2x, e1x, p2y * e1y), len1 = fmaf(e1x, e1x, e1y * e1y);
            float dot2 = fmaf(p0x, e2x, p0y * e2y), len2 = fmaf(e2x, e2x, e2y * e2y);
            float c0 = (dot0 >= 0.0f && dot0 <= len0) ? L0 * L0 : 1e30f;
            float c1 = (dot1 >= 0.0f && dot1 <= len1) ? L1 * L1 : 1e30f;
            float c2 = (dot2 >= 0.0f && dot2 <= len2) ? L2 * L2 : 1e30f;
            float dv0 = fmaf(p0x, p0x, p0y * p0y);
            float dv1 = fmaf(p1x, p1x, p1y * p1y);
            float dv2 = fmaf(p2x, p2x, p2y * p2y);
            float d2 = fminf(fminf(fminf(c0, c1), fminf(c2, dv0)), fminf(dv1, dv2));
            float p = __expf(-kDelta * d2);
            p = fminf(p, 1.0f - 1e-7f);
            float lp = __logf(1.0f - p);  // == log1p(-p) over admitted range
            lm += need ? lp : 0.0f;
        }
    }
    lm = fmaf((float)icnt, kLogInside, lm);

    // merge via LDS atomics: key = (zmap(z) << 32) | (511 - k); max => first-max
    if (besti >= 0) {
        unsigned long long key = ((unsigned long long)zmap(bestz) << 32) |
                                 (unsigned long long)(511 - besti);
        atomicMax(&s_best[lane], key);
    }
    atomicAdd(&s_lm[lane], lm);
    __syncthreads();

    // ---------- reduce + fragment prep (wave 0) ----------
    if (tid < 64) {
        unsigned long long key = s_best[tid];
        float improb = 1.0f - expf(s_lm[tid]);
        float u = 0.0f, v = 0.0f, mk = 0.0f;
        if (key != 0ull) {
            int bi = 511 - (int)(key & 0xFFFFFFFFull);
            int slot = ((bi & 7) << 6) | (bi >> 3);
            float4 vv = sV[slot];
            float4 h0 = sA[slot];
            float4 h1 = sB[slot];
            float D = fmaf(h0.x, h1.x, -h0.w * h0.y);
            float rD = __builtin_amdgcn_rcpf(D);
            float v2x = (h0.y * h1.y - h1.x * h0.z) * rD;
            float v2y = (h0.w * h0.z - h0.x * h1.y) * rD;
            float x0 = vv.x, y0 = vv.y, x1 = vv.z, y1 = vv.w;
            float area = (x1 - x0) * (v2y - y0) - (y1 - y0) * (v2x - x0);
            float inv_a = 1.0f / area;
            // reference formulation (v2 derived, err ~1e-6 -> negligible)
            float w0 = ((v2x - x1) * (py - y1) - (v2y - y1) * (px - x1)) * inv_a;
            float w1 = ((x0 - v2x) * (py - v2y) - (y0 - v2y) * (px - v2x)) * inv_a;
            float w2 = ((x1 - x0) * (py - y0) - (y1 - y0) * (px - x0)) * inv_a;
            ushort4 j = s_j3[slot];
            u = w0 * s_uv[j.x * 2] + w1 * s_uv[j.y * 2] + w2 * s_uv[j.z * 2];
            v = w0 * s_uv[j.x * 2 + 1] + w1 * s_uv[j.y * 2 + 1] + w2 * s_uv[j.z * 2 + 1];
            mk = w0 + w1 + w2;
        }
        float uc = fminf(fmaxf(u, 0.0f), 1.0f);
        float vc = fminf(fmaxf(v, 0.0f), 1.0f);
        float fx = uc * (float)(kTW - 1);
        float fy = (1.0f - vc) * (float)(kTH - 1);
        int xi0 = (int)floorf(fx), yi0 = (int)floorf(fy);
        int xi1 = min(xi0 + 1, kTW - 1), yi1 = min(yi0 + 1, kTH - 1);
        float wx = fx - (float)xi0, wy = fy - (float)yi0;
        float w00 = (1.0f - wx) * (1.0f - wy) * mk;
        float w01 = wx * (1.0f - wy) * mk;
        float w10 = (1.0f - wx) * wy * mk;
        float w11 = wx * wy * mk;
        s_pxW[tid] = make_float4(w00, w01, w10, w11);   // aliases sA (dead)
        s_pxO[tid] = make_int4(yi0 * kTW + xi0, yi0 * kTW + xi1,
                               yi1 * kTW + xi0, yi1 * kTW + xi1);
        out[kB * kH * kW * 3 + (b * kH + pyi) * kW + pxi] = improb;
    }
    __syncthreads();

    // ---------- fragment shader: 192 threads = 64 px x 3 channels ----------
    if (tid < 192) {
        int pix = tid & 63;
        int c = tid >> 6;
        float4 w = s_pxW[pix];
        int4 o = s_pxO[pix];
        const float* tc = tex + ((size_t)b * 3 + c) * kTH * kTW;
        float col = tc[o.x] * w.x + tc[o.y] * w.y + tc[o.z] * w.z + tc[o.w] * w.w;
        int qy = ty * 8 + (pix >> 3);
        int qx = tx * 8 + (pix & 7);
        out[((b * kH + qy) * kW + qx) * 3 + c] = col;
    }
}

extern "C" void kernel_launch(void* const* d_in, const int* in_sizes, int n_in,
                              void* d_out, int out_size, void* d_ws, size_t ws_size,
                              hipStream_t stream) {
    const float* pts = (const float*)d_in[0];
    const int* faces = (const int*)d_in[1];
    const float* uvs = (const float*)d_in[2];
    const float* tex = (const float*)d_in[3];
    float* out = (float*)d_out;
    render_all<<<kB * 256, 512, 0, stream>>>(pts, faces, uvs, tex, out);
}

// Round 12
// 17.643 us; speedup vs baseline: 1.2306x; 1.0402x over previous
//
#include <hip/hip_runtime.h>
#include <math.h>

constexpr int kB = 2, kP = 300, kF = 512, kH = 128, kW = 128, kTH = 512, kTW = 512;
constexpr float kDelta = 7000.0f;
constexpr float kCut = 0.0363f;    // skip p < ~1e-4 contributions (improb err <= ~1e-3)
constexpr float kThr2 = 0.012928f; // (kCut + 0.0774 pixel-center tile radius)^2
constexpr float kIntThr = 0.0785f; // minL(center) >= this -> ALL pixels inside
constexpr float kLogInside = -15.9423847f; // log1p(-(1-1e-7f)) = ln(2^-23)

__device__ __forceinline__ unsigned zmap(float f) {
    unsigned b = __float_as_uint(f);
    return (b & 0x80000000u) ? ~b : (b | 0x80000000u);  // order-preserving float->uint
}

// One fused kernel. Grid: 512 blocks = 2 batches x 256 tiles (8x8 px).
// Block: 512 threads = 8 waves. Compacted front-face k DEALT to slot
// (k&7)*64+(k>>3); wave wv owns slots [wv*64,wv*64+64) = faces k===wv (mod 8).
// Per-face LDS records (8 x float4):
//  F0=(A0,B0,C0,A1) F1=(B1,C1,A2,B2) F2=(C2,az,bz,cz)   L_i = unit-normal line dist
//  F3=(T0x,T0y,T0c,len0) F4=(T1..) F5=(T2..)            s_i = tangential affine
//  F6=(ua,ub,uc,-) F7=(va,vb,vc,-)                      u,v affine
// Identities: seg_i dist^2 = L_i^2 (if s_i in [0,len_i]); vertex dist^2 = L_i^2+s_i^2.
__global__ __launch_bounds__(512, 4) void render_all(const float* __restrict__ pts,
                                                     const int* __restrict__ faces,
                                                     const float* __restrict__ uvs,
                                                     const float* __restrict__ tex,
                                                     float* __restrict__ out) {
    __shared__ float4 sF[8][kF];                   // 64 KB
    __shared__ unsigned long long s_best[64];      // 512 B packed (z | 511-k)
    __shared__ float s_lm[64];                     // 256 B log-miss accum
    __shared__ int s_wsum[8];
    float4* s_pxW = sF[0];                         // aliases (F0 dead post-loop)
    int4* s_pxO = (int4*)(sF[0] + 64);

    int tile = (int)blockIdx.x;
    int b = tile >> 8;
    int rem = tile & 255;
    int ty = rem >> 4, tx = rem & 15;
    int tid = (int)threadIdx.x;
    int lane = tid & 63;
    int wv = tid >> 6;

    // ---------- setup: thread tid processes face tid for batch b ----------
    {
        int f = tid;
        int i0 = faces[f * 3 + 0], i1 = faces[f * 3 + 1], i2 = faces[f * 3 + 2];
        const float* pb = pts + b * kP * 3;
        float x0 = pb[i0 * 3], y0 = pb[i0 * 3 + 1], z0 = pb[i0 * 3 + 2];
        float x1 = pb[i1 * 3], y1 = pb[i1 * 3 + 1], z1 = pb[i1 * 3 + 2];
        float x2 = pb[i2 * 3], y2 = pb[i2 * 3 + 1], z2 = pb[i2 * 3 + 2];
        const float* ub = uvs + b * (kP * 2);
        float u0 = ub[i0 * 2], vv0 = ub[i0 * 2 + 1];
        float u1 = ub[i1 * 2], vv1 = ub[i1 * 2 + 1];
        float u2 = ub[i2 * 2], vv2 = ub[i2 * 2 + 1];
        float area = (x1 - x0) * (y2 - y0) - (y1 - y0) * (x2 - x0);
        bool front = area > 1e-8f;

        if (tid < 64) { s_best[tid] = 0ull; s_lm[tid] = 0.0f; }
        // prefill rows F0..F2: empty slots -> L=-1e30 (never inside/admitted);
        // d2c terms become ~1e60 regardless of garbage in F3..F5 (L^2 dominates).
        sF[0][f] = make_float4(0.0f, 0.0f, -1e30f, 0.0f);
        sF[1][f] = make_float4(0.0f, -1e30f, 0.0f, 0.0f);
        sF[2][f] = make_float4(-1e30f, 0.0f, 0.0f, 0.0f);
        unsigned long long bal = __ballot(front);
        if (lane == 0) s_wsum[wv] = __popcll(bal);
        __syncthreads();  // wsum + prefill + inits visible

        int base = 0;
#pragma unroll
        for (int w = 0; w < 8; ++w) base += (w < wv) ? s_wsum[w] : 0;
        int k = base + __popcll(bal & ((1ull << lane) - 1ull));  // compacted idx

        if (front) {
            int slot = ((k & 7) << 6) | (k >> 3);  // deal across waves
            float inv_a = 1.0f / area;
            float e0x = x2 - x1, e0y = y2 - y1;
            float e1x = x0 - x2, e1y = y0 - y2;
            float e2x = x1 - x0, e2y = y1 - y0;
            float l0 = fmaf(e0x, e0x, e0y * e0y);
            float l1 = fmaf(e1x, e1x, e1y * e1y);
            float l2 = fmaf(e2x, e2x, e2y * e2y);
            float s0 = rsqrtf(l0 + 1e-12f);
            float s1 = rsqrtf(l1 + 1e-12f);
            float s2 = rsqrtf(l2 + 1e-12f);
            float A0 = -e0y * s0, B0 = e0x * s0, C0 = (e0y * x1 - e0x * y1) * s0;
            float A1 = -e1y * s1, B1 = e1x * s1, C1 = (e1y * x2 - e1x * y2) * s1;
            float A2 = -e2y * s2, B2 = e2x * s2, C2 = (e2y * x0 - e2x * y0) * s2;
            float a0 = -e0y * inv_a, b0 = e0x * inv_a, c0 = (e0y * x1 - e0x * y1) * inv_a;
            float a1 = -e1y * inv_a, b1 = e1x * inv_a, c1 = (e1y * x2 - e1x * y2) * inv_a;
            float a2 = -e2y * inv_a, b2 = e2x * inv_a, c2 = (e2y * x0 - e2x * y0) * inv_a;
            sF[0][slot] = make_float4(A0, B0, C0, A1);
            sF[1][slot] = make_float4(B1, C1, A2, B2);
            sF[2][slot] = make_float4(C2,
                                      a0 * z0 + a1 * z1 + a2 * z2,
                                      b0 * z0 + b1 * z1 + b2 * z2,
                                      c0 * z0 + c1 * z1 + c2 * z2);
            // tangential affines: s_i(p) = T_i . p + Tc_i, measured from edge start
            sF[3][slot] = make_float4(e0x * s0, e0y * s0,
                                      -(e0x * x1 + e0y * y1) * s0, l0 * s0);  // from v1
            sF[4][slot] = make_float4(e1x * s1, e1y * s1,
                                      -(e1x * x2 + e1y * y2) * s1, l1 * s1);  // from v2
            sF[5][slot] = make_float4(e2x * s2, e2y * s2,
                                      -(e2x * x0 + e2y * y0) * s2, l2 * s2);  // from v0
            sF[6][slot] = make_float4(a0 * u0 + a1 * u1 + a2 * u2,
                                      b0 * u0 + b1 * u1 + b2 * u2,
                                      c0 * u0 + c1 * u1 + c2 * u2, 0.0f);
            sF[7][slot] = make_float4(a0 * vv0 + a1 * vv1 + a2 * vv2,
                                      b0 * vv0 + b1 * vv1 + b2 * vv2,
                                      c0 * vv0 + c1 * vv1 + c2 * vv2, 0.0f);
        }
    }
    __syncthreads();

    // ---------- render ----------
    int pyi = ty * 8 + (lane >> 3);
    int pxi = tx * 8 + (lane & 7);
    float px = ((float)pxi + 0.5f) * (2.0f / 128.0f) - 1.0f;
    float py = 1.0f - ((float)pyi + 0.5f) * (2.0f / 128.0f);

    // cull at tile center: exact dist-to-triangle via L/s identities
    float cx = (float)(tx * 8 + 4) * (2.0f / 128.0f) - 1.0f;
    float cy = 1.0f - (float)(ty * 8 + 4) * (2.0f / 128.0f);
    unsigned long long me, mi;
    {
        int slt = (wv << 6) + lane;
        float4 a4 = sF[0][slt];
        float4 b4 = sF[1][slt];
        float4 c4 = sF[2][slt];
        float4 t0 = sF[3][slt];
        float4 t1 = sF[4][slt];
        float4 t2 = sF[5][slt];
        float L0 = fmaf(a4.x, cx, fmaf(a4.y, cy, a4.z));
        float L1 = fmaf(a4.w, cx, fmaf(b4.x, cy, b4.y));
        float L2 = fmaf(b4.z, cx, fmaf(b4.w, cy, c4.x));
        float minc = fminf(fminf(L0, L1), L2);
        float s0 = fmaf(t0.x, cx, fmaf(t0.y, cy, t0.z));
        float s1 = fmaf(t1.x, cx, fmaf(t1.y, cy, t1.z));
        float s2 = fmaf(t2.x, cx, fmaf(t2.y, cy, t2.z));
        float q0 = L0 * L0, q1 = L1 * L1, q2 = L2 * L2;
        float c0 = (s0 >= 0.0f && s0 <= t0.w) ? q0 : 1e30f;
        float c1 = (s1 >= 0.0f && s1 <= t1.w) ? q1 : 1e30f;
        float c2 = (s2 >= 0.0f && s2 <= t2.w) ? q2 : 1e30f;
        float dv1 = fmaf(s0, s0, q0);   // dist^2 to v1 (edge0 start)
        float dv2 = fmaf(s1, s1, q1);   // v2
        float dv0 = fmaf(s2, s2, q2);   // v0
        float d2c = fminf(fminf(fminf(c0, c1), fminf(c2, dv0)), fminf(dv1, dv2));
        bool inter = minc >= kIntThr;                       // all 64 px inside
        bool admit = (minc >= 0.0f) | (d2c <= kThr2);
        mi = __ballot(inter);
        me = __ballot(admit && !inter);
    }

    float bestz = -1e9f;
    int besti = 1 << 30, icnt = 0;
    float lm = 0.0f;

    // interior loop: z-argmax only (1 read + ~10 VALU per face)
    icnt += (int)__popcll(mi);   // every pixel inside; lm handled via icnt
    while (mi) {
        int l = (int)__builtin_ctzll(mi);
        mi &= (mi - 1);
        int fs = (wv << 6) + l;
        int k = (l << 3) | wv;
        float4 h2 = sF[2][fs];
        float z = fmaf(h2.y, px, fmaf(h2.z, py, h2.w));
        if (z > bestz || (z == bestz && k < besti)) { bestz = z; besti = k; }
    }

    // edge loop: full inside/band path
    while (me) {
        int l = (int)__builtin_ctzll(me);
        me &= (me - 1);
        int fs = (wv << 6) + l;
        int k = (l << 3) | wv;
        float4 h0 = sF[0][fs];
        float4 h1 = sF[1][fs];
        float4 h2 = sF[2][fs];
        float L0 = fmaf(h0.x, px, fmaf(h0.y, py, h0.z));
        float L1 = fmaf(h0.w, px, fmaf(h1.x, py, h1.y));
        float L2 = fmaf(h1.z, px, fmaf(h1.w, py, h2.x));
        float minL = fminf(fminf(L0, L1), L2);
        bool inside = minL >= 0.0f;
        float z = fmaf(h2.y, px, fmaf(h2.z, py, h2.w));
        if (inside && (z > bestz || (z == bestz && k < besti))) { bestz = z; besti = k; }
        icnt += inside ? 1 : 0;
        float db = fminf(fminf(fabsf(L0), fabsf(L1)), fabsf(L2));
        bool need = (!inside) & (db < kCut);
        if (__any(need)) {
            float4 t0 = sF[3][fs];
            float4 t1 = sF[4][fs];
            float4 t2 = sF[5][fs];
            float s0 = fmaf(t0.x, px, fmaf(t0.y, py, t0.z));
            float s1 = fmaf(t1.x, px, fmaf(t1.y, py, t1.z));
            float s2 = fmaf(t2.x, px, fmaf(t2.y, py, t2.z));
            float q0 = L0 * L0, q1 = L1 * L1, q2 = L2 * L2;
            float c0 = (s0 >= 0.0f && s0 <= t0.w) ? q0 : 1e30f;
            float c1 = (s1 >= 0.0f && s1 <= t1.w) ? q1 : 1e30f;
            float c2 = (s2 >= 0.0f && s2 <= t2.w) ? q2 : 1e30f;
            float dv1 = fmaf(s0, s0, q0);
            float dv2 = fmaf(s1, s1, q1);
            float dv0 = fmaf(s2, s2, q2);
            float d2 = fminf(fminf(fminf(c0, c1), fminf(c2, dv0)), fminf(dv1, dv2));
            float p = __expf(-kDelta * d2);
            p = fminf(p, 1.0f - 1e-7f);
            float lp = __logf(1.0f - p);  // == log1p(-p) over admitted range
            lm += need ? lp : 0.0f;
        }
    }
    lm = fmaf((float)icnt, kLogInside, lm);

    // merge via LDS atomics: key = (zmap(z) << 32) | (511 - k); max => first-max
    if (besti < (1 << 30)) {
        unsigned long long key = ((unsigned long long)zmap(bestz) << 32) |
                                 (unsigned long long)(511 - besti);
        atomicMax(&s_best[lane], key);
    }
    atomicAdd(&s_lm[lane], lm);
    __syncthreads();

    // ---------- reduce + fragment prep (wave 0) ----------
    if (tid < 64) {
        unsigned long long key = s_best[tid];
        float improb = 1.0f - expf(s_lm[tid]);
        float u = 0.0f, v = 0.0f, mk = 0.0f;
        if (key != 0ull) {
            int bi = 511 - (int)(key & 0xFFFFFFFFull);
            int slot = ((bi & 7) << 6) | (bi >> 3);
            float4 uq = sF[6][slot];
            float4 vq = sF[7][slot];
            u = fmaf(uq.x, px, fmaf(uq.y, py, uq.z));
            v = fmaf(vq.x, px, fmaf(vq.y, py, vq.z));
            mk = 1.0f;  // mask = w0+w1+w2 == 1 exactly in exact math (err ~2e-7)
        }
        float uc = fminf(fmaxf(u, 0.0f), 1.0f);
        float vc = fminf(fmaxf(v, 0.0f), 1.0f);
        float fx = uc * (float)(kTW - 1);
        float fy = (1.0f - vc) * (float)(kTH - 1);
        int xi0 = (int)floorf(fx), yi0 = (int)floorf(fy);
        int xi1 = min(xi0 + 1, kTW - 1), yi1 = min(yi0 + 1, kTH - 1);
        float wx = fx - (float)xi0, wy = fy - (float)yi0;
        float w00 = (1.0f - wx) * (1.0f - wy) * mk;
        float w01 = wx * (1.0f - wy) * mk;
        float w10 = (1.0f - wx) * wy * mk;
        float w11 = wx * wy * mk;
        s_pxW[tid] = make_float4(w00, w01, w10, w11);   // aliases F0 (dead)
        s_pxO[tid] = make_int4(yi0 * kTW + xi0, yi0 * kTW + xi1,
                               yi1 * kTW + xi0, yi1 * kTW + xi1);
        out[kB * kH * kW * 3 + (b * kH + pyi) * kW + pxi] = improb;
    }
    __syncthreads();

    // ---------- fragment shader: 192 threads = 64 px x 3 channels ----------
    if (tid < 192) {
        int pix = tid & 63;
        int c = tid >> 6;
        float4 w = s_pxW[pix];
        int4 o = s_pxO[pix];
        const float* tc = tex + ((size_t)b * 3 + c) * kTH * kTW;
        float col = tc[o.x] * w.x + tc[o.y] * w.y + tc[o.z] * w.z + tc[o.w] * w.w;
        int qy = ty * 8 + (pix >> 3);
        int qx = tx * 8 + (pix & 7);
        out[((b * kH + qy) * kW + qx) * 3 + c] = col;
    }
}

extern "C" void kernel_launch(void* const* d_in, const int* in_sizes, int n_in,
                              void* d_out, int out_size, void* d_ws, size_t ws_size,
                              hipStream_t stream) {
    const float* pts = (const float*)d_in[0];
    const int* faces = (const int*)d_in[1];
    const float* uvs = (const float*)d_in[2];
    const float* tex = (const float*)d_in[3];
    float* out = (float*)d_out;
    render_all<<<kB * 256, 512, 0, stream>>>(pts, faces, uvs, tex, out);
}

// Round 13
// 17.248 us; speedup vs baseline: 1.2588x; 1.0229x over previous
//
#include <hip/hip_runtime.h>
#include <math.h>

constexpr int kB = 2, kP = 300, kF = 512, kH = 128, kW = 128, kTH = 512, kTW = 512;
constexpr float kDelta = 7000.0f;
constexpr float kCut = 0.0363f;    // skip p < ~1e-4 contributions (improb err <= ~1e-3)
constexpr float kThr2 = 0.012928f; // (kCut + 0.0774 pixel-center tile radius)^2
constexpr float kIntThr = 0.0785f; // minL(center) >= this -> ALL pixels inside
constexpr float kLogInside = -15.9423847f; // log1p(-(1-1e-7f)) = ln(2^-23)

__device__ __forceinline__ unsigned zmap(float f) {
    unsigned b = __float_as_uint(f);
    return (b & 0x80000000u) ? ~b : (b | 0x80000000u);  // order-preserving float->uint
}

// One fused kernel. Grid: 512 blocks = 2 batches x 256 tiles (8x8 px).
// Block: 512 threads = 8 waves. Compacted front-face k DEALT to slot
// (k&7)*64+(k>>3); wave wv owns slots [wv*64,wv*64+64) = faces k===wv (mod 8).
// Per-face LDS records (8 x float4):
//  F0=(A0,B0,C0,A1) F1=(B1,C1,A2,B2) F2=(C2,az,bz,cz)   L_i = unit-normal line dist
//  F3=(T0x,T0y,T0c,len0) F4=(T1..) F5=(T2..)            s_i = tangential affine
//  F6=(ua,ub,uc,-) F7=(va,vb,vc,-)                      u,v affine
// Identities: seg_i dist^2 = L_i^2 (if s_i in [0,len_i]); vertex dist^2 = L_i^2+s_i^2.
// Edge loop is BRANCHLESS: non-band faces get d2=30 -> exp -> 0 -> log(1)=0.
__global__ __launch_bounds__(512, 4) void render_all(const float* __restrict__ pts,
                                                     const int* __restrict__ faces,
                                                     const float* __restrict__ uvs,
                                                     const float* __restrict__ tex,
                                                     float* __restrict__ out) {
    __shared__ float4 sF[8][kF];                   // 64 KB
    __shared__ unsigned long long s_best[64];      // 512 B packed (z | 511-k)
    __shared__ float s_lm[64];                     // 256 B log-miss accum
    __shared__ int s_wsum[8];
    float4* s_pxW = sF[0];                         // aliases (F0 dead post-loop)
    int4* s_pxO = (int4*)(sF[0] + 64);

    int tile = (int)blockIdx.x;
    int b = tile >> 8;
    int rem = tile & 255;
    int ty = rem >> 4, tx = rem & 15;
    int tid = (int)threadIdx.x;
    int lane = tid & 63;
    int wv = tid >> 6;

    // ---------- setup: thread tid processes face tid for batch b ----------
    {
        int f = tid;
        int i0 = faces[f * 3 + 0], i1 = faces[f * 3 + 1], i2 = faces[f * 3 + 2];
        const float* pb = pts + b * kP * 3;
        float x0 = pb[i0 * 3], y0 = pb[i0 * 3 + 1], z0 = pb[i0 * 3 + 2];
        float x1 = pb[i1 * 3], y1 = pb[i1 * 3 + 1], z1 = pb[i1 * 3 + 2];
        float x2 = pb[i2 * 3], y2 = pb[i2 * 3 + 1], z2 = pb[i2 * 3 + 2];
        const float* ub = uvs + b * (kP * 2);
        float u0 = ub[i0 * 2], vv0 = ub[i0 * 2 + 1];
        float u1 = ub[i1 * 2], vv1 = ub[i1 * 2 + 1];
        float u2 = ub[i2 * 2], vv2 = ub[i2 * 2 + 1];
        float area = (x1 - x0) * (y2 - y0) - (y1 - y0) * (x2 - x0);
        bool front = area > 1e-8f;

        if (tid < 64) { s_best[tid] = 0ull; s_lm[tid] = 0.0f; }
        // prefill rows F0..F2: empty slots -> L=-1e30 (never inside/admitted);
        // cull's fminf chain drops NaN garbage from uninitialized F3..F5.
        sF[0][f] = make_float4(0.0f, 0.0f, -1e30f, 0.0f);
        sF[1][f] = make_float4(0.0f, -1e30f, 0.0f, 0.0f);
        sF[2][f] = make_float4(-1e30f, 0.0f, 0.0f, 0.0f);
        unsigned long long bal = __ballot(front);
        if (lane == 0) s_wsum[wv] = __popcll(bal);
        __syncthreads();  // wsum + prefill + inits visible

        int base = 0;
#pragma unroll
        for (int w = 0; w < 8; ++w) base += (w < wv) ? s_wsum[w] : 0;
        int k = base + __popcll(bal & ((1ull << lane) - 1ull));  // compacted idx

        if (front) {
            int slot = ((k & 7) << 6) | (k >> 3);  // deal across waves
            float inv_a = 1.0f / area;
            float e0x = x2 - x1, e0y = y2 - y1;
            float e1x = x0 - x2, e1y = y0 - y2;
            float e2x = x1 - x0, e2y = y1 - y0;
            float l0 = fmaf(e0x, e0x, e0y * e0y);
            float l1 = fmaf(e1x, e1x, e1y * e1y);
            float l2 = fmaf(e2x, e2x, e2y * e2y);
            float s0 = rsqrtf(l0 + 1e-12f);
            float s1 = rsqrtf(l1 + 1e-12f);
            float s2 = rsqrtf(l2 + 1e-12f);
            float A0 = -e0y * s0, B0 = e0x * s0, C0 = (e0y * x1 - e0x * y1) * s0;
            float A1 = -e1y * s1, B1 = e1x * s1, C1 = (e1y * x2 - e1x * y2) * s1;
            float A2 = -e2y * s2, B2 = e2x * s2, C2 = (e2y * x0 - e2x * y0) * s2;
            float a0 = -e0y * inv_a, b0 = e0x * inv_a, c0 = (e0y * x1 - e0x * y1) * inv_a;
            float a1 = -e1y * inv_a, b1 = e1x * inv_a, c1 = (e1y * x2 - e1x * y2) * inv_a;
            float a2 = -e2y * inv_a, b2 = e2x * inv_a, c2 = (e2y * x0 - e2x * y0) * inv_a;
            sF[0][slot] = make_float4(A0, B0, C0, A1);
            sF[1][slot] = make_float4(B1, C1, A2, B2);
            sF[2][slot] = make_float4(C2,
                                      a0 * z0 + a1 * z1 + a2 * z2,
                                      b0 * z0 + b1 * z1 + b2 * z2,
                                      c0 * z0 + c1 * z1 + c2 * z2);
            // tangential affines: s_i(p) = T_i . p + Tc_i, measured from edge start
            sF[3][slot] = make_float4(e0x * s0, e0y * s0,
                                      -(e0x * x1 + e0y * y1) * s0, l0 * s0);  // from v1
            sF[4][slot] = make_float4(e1x * s1, e1y * s1,
                                      -(e1x * x2 + e1y * y2) * s1, l1 * s1);  // from v2
            sF[5][slot] = make_float4(e2x * s2, e2y * s2,
                                      -(e2x * x0 + e2y * y0) * s2, l2 * s2);  // from v0
            sF[6][slot] = make_float4(a0 * u0 + a1 * u1 + a2 * u2,
                                      b0 * u0 + b1 * u1 + b2 * u2,
                                      c0 * u0 + c1 * u1 + c2 * u2, 0.0f);
            sF[7][slot] = make_float4(a0 * vv0 + a1 * vv1 + a2 * vv2,
                                      b0 * vv0 + b1 * vv1 + b2 * vv2,
                                      c0 * vv0 + c1 * vv1 + c2 * vv2, 0.0f);
        }
    }
    __syncthreads();

    // ---------- render ----------
    int pyi = ty * 8 + (lane >> 3);
    int pxi = tx * 8 + (lane & 7);
    float px = ((float)pxi + 0.5f) * (2.0f / 128.0f) - 1.0f;
    float py = 1.0f - ((float)pyi + 0.5f) * (2.0f / 128.0f);

    // cull at tile center: exact dist-to-triangle via L/s identities
    float cx = (float)(tx * 8 + 4) * (2.0f / 128.0f) - 1.0f;
    float cy = 1.0f - (float)(ty * 8 + 4) * (2.0f / 128.0f);
    unsigned long long me, mi;
    {
        int slt = (wv << 6) + lane;
        float4 a4 = sF[0][slt];
        float4 b4 = sF[1][slt];
        float4 c4 = sF[2][slt];
        float4 t0 = sF[3][slt];
        float4 t1 = sF[4][slt];
        float4 t2 = sF[5][slt];
        float L0 = fmaf(a4.x, cx, fmaf(a4.y, cy, a4.z));
        float L1 = fmaf(a4.w, cx, fmaf(b4.x, cy, b4.y));
        float L2 = fmaf(b4.z, cx, fmaf(b4.w, cy, c4.x));
        float minc = fminf(fminf(L0, L1), L2);
        float s0 = fmaf(t0.x, cx, fmaf(t0.y, cy, t0.z));
        float s1 = fmaf(t1.x, cx, fmaf(t1.y, cy, t1.z));
        float s2 = fmaf(t2.x, cx, fmaf(t2.y, cy, t2.z));
        float q0 = L0 * L0, q1 = L1 * L1, q2 = L2 * L2;
        float c0 = (s0 >= 0.0f && s0 <= t0.w) ? q0 : 1e30f;
        float c1 = (s1 >= 0.0f && s1 <= t1.w) ? q1 : 1e30f;
        float c2 = (s2 >= 0.0f && s2 <= t2.w) ? q2 : 1e30f;
        float dv1 = fmaf(s0, s0, q0);   // dist^2 to v1 (edge0 start)
        float dv2 = fmaf(s1, s1, q1);   // v2
        float dv0 = fmaf(s2, s2, q2);   // v0
        float d2c = fminf(fminf(fminf(c0, c1), fminf(c2, dv0)), fminf(dv1, dv2));
        bool inter = minc >= kIntThr;                       // all 64 px inside
        bool admit = (minc >= 0.0f) | (d2c <= kThr2);
        mi = __ballot(inter);
        me = __ballot(admit && !inter);
    }

    float bestz = -1e9f;
    int besti = 1 << 30, icnt = 0;
    float lm = 0.0f;

    // interior loop: z-argmax only (1 read + ~10 VALU per face)
    icnt += (int)__popcll(mi);   // every pixel inside; lm handled via icnt
    while (mi) {
        int l = (int)__builtin_ctzll(mi);
        mi &= (mi - 1);
        int fs = (wv << 6) + l;
        int k = (l << 3) | wv;
        float4 h2 = sF[2][fs];
        float z = fmaf(h2.y, px, fmaf(h2.z, py, h2.w));
        if (z > bestz || (z == bestz && k < besti)) { bestz = z; besti = k; }
    }

    // edge loop: BRANCHLESS full path (no __any, no per-iteration branch)
    while (me) {
        int l = (int)__builtin_ctzll(me);
        me &= (me - 1);
        int fs = (wv << 6) + l;
        int k = (l << 3) | wv;
        float4 h0 = sF[0][fs];
        float4 h1 = sF[1][fs];
        float4 h2 = sF[2][fs];
        float4 t0 = sF[3][fs];
        float4 t1 = sF[4][fs];
        float4 t2 = sF[5][fs];
        float L0 = fmaf(h0.x, px, fmaf(h0.y, py, h0.z));
        float L1 = fmaf(h0.w, px, fmaf(h1.x, py, h1.y));
        float L2 = fmaf(h1.z, px, fmaf(h1.w, py, h2.x));
        float minL = fminf(fminf(L0, L1), L2);
        bool inside = minL >= 0.0f;
        float z = fmaf(h2.y, px, fmaf(h2.z, py, h2.w));
        if (inside && (z > bestz || (z == bestz && k < besti))) { bestz = z; besti = k; }
        icnt += inside ? 1 : 0;
        float s0 = fmaf(t0.x, px, fmaf(t0.y, py, t0.z));
        float s1 = fmaf(t1.x, px, fmaf(t1.y, py, t1.z));
        float s2 = fmaf(t2.x, px, fmaf(t2.y, py, t2.z));
        float q0 = L0 * L0, q1 = L1 * L1, q2 = L2 * L2;
        float c0 = (s0 >= 0.0f && s0 <= t0.w) ? q0 : 1e30f;
        float c1 = (s1 >= 0.0f && s1 <= t1.w) ? q1 : 1e30f;
        float c2 = (s2 >= 0.0f && s2 <= t2.w) ? q2 : 1e30f;
        float dv1 = fmaf(s0, s0, q0);
        float dv2 = fmaf(s1, s1, q1);
        float dv0 = fmaf(s2, s2, q2);
        float d2 = fminf(fminf(fminf(c0, c1), fminf(c2, dv0)), fminf(dv1, dv2));
        bool need = (!inside) & (fminf(fminf(fabsf(L0), fabsf(L1)), fabsf(L2)) < kCut);
        d2 = need ? d2 : 30.0f;        // exp(-7000*30) == 0 -> log(1-0) == 0
        float p = __expf(-kDelta * d2);
        p = fminf(p, 1.0f - 1e-7f);
        lm += __logf(1.0f - p);        // == log1p(-p) over admitted range
    }
    lm = fmaf((float)icnt, kLogInside, lm);

    // merge via LDS atomics: key = (zmap(z) << 32) | (511 - k); max => first-max
    if (besti < (1 << 30)) {
        unsigned long long key = ((unsigned long long)zmap(bestz) << 32) |
                                 (unsigned long long)(511 - besti);
        atomicMax(&s_best[lane], key);
    }
    atomicAdd(&s_lm[lane], lm);
    __syncthreads();

    // ---------- reduce + fragment prep (wave 0) ----------
    if (tid < 64) {
        unsigned long long key = s_best[tid];
        float improb = 1.0f - expf(s_lm[tid]);
        float u = 0.0f, v = 0.0f, mk = 0.0f;
        if (key != 0ull) {
            int bi = 511 - (int)(key & 0xFFFFFFFFull);
            int slot = ((bi & 7) << 6) | (bi >> 3);
            float4 uq = sF[6][slot];
            float4 vq = sF[7][slot];
            u = fmaf(uq.x, px, fmaf(uq.y, py, uq.z));
            v = fmaf(vq.x, px, fmaf(vq.y, py, vq.z));
            mk = 1.0f;  // mask = w0+w1+w2 == 1 exactly in exact math (err ~2e-7)
        }
        float uc = fminf(fmaxf(u, 0.0f), 1.0f);
        float vc = fminf(fmaxf(v, 0.0f), 1.0f);
        float fx = uc * (float)(kTW - 1);
        float fy = (1.0f - vc) * (float)(kTH - 1);
        int xi0 = (int)floorf(fx), yi0 = (int)floorf(fy);
        int xi1 = min(xi0 + 1, kTW - 1), yi1 = min(yi0 + 1, kTH - 1);
        float wx = fx - (float)xi0, wy = fy - (float)yi0;
        float w00 = (1.0f - wx) * (1.0f - wy) * mk;
        float w01 = wx * (1.0f - wy) * mk;
        float w10 = (1.0f - wx) * wy * mk;
        float w11 = wx * wy * mk;
        s_pxW[tid] = make_float4(w00, w01, w10, w11);   // aliases F0 (dead)
        s_pxO[tid] = make_int4(yi0 * kTW + xi0, yi0 * kTW + xi1,
                               yi1 * kTW + xi0, yi1 * kTW + xi1);
        out[kB * kH * kW * 3 + (b * kH + pyi) * kW + pxi] = improb;
    }
    __syncthreads();

    // ---------- fragment shader: 192 threads = 64 px x 3 channels ----------
    if (tid < 192) {
        int pix = tid & 63;
        int c = tid >> 6;
        float4 w = s_pxW[pix];
        int4 o = s_pxO[pix];
        const float* tc = tex + ((size_t)b * 3 + c) * kTH * kTW;
        float col = tc[o.x] * w.x + tc[o.y] * w.y + tc[o.z] * w.z + tc[o.w] * w.w;
        int qy = ty * 8 + (pix >> 3);
        int qx = tx * 8 + (pix & 7);
        out[((b * kH + qy) * kW + qx) * 3 + c] = col;
    }
}

extern "C" void kernel_launch(void* const* d_in, const int* in_sizes, int n_in,
                              void* d_out, int out_size, void* d_ws, size_t ws_size,
                              hipStream_t stream) {
    const float* pts = (const float*)d_in[0];
    const int* faces = (const int*)d_in[1];
    const float* uvs = (const float*)d_in[2];
    const float* tex = (const float*)d_in[3];
    float* out = (float*)d_out;
    render_all<<<kB * 256, 512, 0, stream>>>(pts, faces, uvs, tex, out);
}